// Round 1
// baseline (2902.093 us; speedup 1.0000x reference)
//
#include <hip/hip_runtime.h>

#define MUL 32
#define N_NODES 50000
#define N_EDGES 800000
#define ROW_OUT 352   // 11*MUL
#define ROW_X 128     // 4*MUL
#define ROW_W 160     // 5*MUL

// 1/sqrt(3), 1/sqrt(2)
#define INV_SQRT3 0.57735026918962576f
#define INV_SQRT2 0.70710678118654752f

// One edge per 32 lanes; lane u owns mul-channel u (u in [0,32)).
// Per lane: 5 coalesced weight loads, 1 coalesced xs0 load, 3 xs1 loads,
// 4-float attr broadcast, 11 atomicAdds into out[dst].
__global__ __launch_bounds__(256) void tp_scatter_kernel(
    const float* __restrict__ x,
    const float* __restrict__ edge_attr,
    const float* __restrict__ edge_weight,
    const int*   __restrict__ edge_dst,
    const int*   __restrict__ edge_src,
    float*       __restrict__ out)
{
    const int tid = blockIdx.x * blockDim.x + threadIdx.x;
    const int e = tid >> 5;
    const int u = tid & 31;
    if (e >= N_EDGES) return;

    const int src = edge_src[e];
    const int dst = edge_dst[e];

    // attr broadcast (16B aligned: edge_attr rows are 4 floats)
    const float4 a = *reinterpret_cast<const float4*>(edge_attr + (size_t)e * 4);
    const float a0  = a.x;
    const float a1x = a.y, a1y = a.z, a1z = a.w;

    const float* wrow = edge_weight + (size_t)e * ROW_W;
    const float w0 = wrow[0 * MUL + u];
    const float w1 = wrow[1 * MUL + u];
    const float w2 = wrow[2 * MUL + u];
    const float w3 = wrow[3 * MUL + u];
    const float w4 = wrow[4 * MUL + u];

    const float* xrow = x + (size_t)src * ROW_X;
    const float xs0 = xrow[u];
    const float x1x = xrow[MUL + u * 3 + 0];
    const float x1y = xrow[MUL + u * 3 + 1];
    const float x1z = xrow[MUL + u * 3 + 2];

    float* orow = out + (size_t)dst * ROW_OUT;

    // o0[u] = w0 * xs0 * a0                          -> [0, 32)
    atomicAdd(orow + u, w0 * xs0 * a0);

    // o1[u,k] = w1 * xs0 * a1[k]                     -> [32, 128)
    const float w1xs0 = w1 * xs0;
    atomicAdd(orow + 1 * MUL + u * 3 + 0, w1xs0 * a1x);
    atomicAdd(orow + 1 * MUL + u * 3 + 1, w1xs0 * a1y);
    atomicAdd(orow + 1 * MUL + u * 3 + 2, w1xs0 * a1z);

    // o2[u,k] = w2 * xs1[u,k] * a0                   -> [128, 224)
    const float w2a0 = w2 * a0;
    atomicAdd(orow + 4 * MUL + u * 3 + 0, w2a0 * x1x);
    atomicAdd(orow + 4 * MUL + u * 3 + 1, w2a0 * x1y);
    atomicAdd(orow + 4 * MUL + u * 3 + 2, w2a0 * x1z);

    // o3[u] = w3 * dot(xs1[u], a1) / sqrt(3)         -> [224, 256)
    const float dot = x1x * a1x + x1y * a1y + x1z * a1z;
    atomicAdd(orow + 7 * MUL + u, w3 * dot * INV_SQRT3);

    // o4[u,k] = w4 * cross(xs1[u], a1)[k] / sqrt(2)  -> [256, 352)
    const float cx = x1y * a1z - x1z * a1y;
    const float cy = x1z * a1x - x1x * a1z;
    const float cz = x1x * a1y - x1y * a1x;
    const float w4s = w4 * INV_SQRT2;
    atomicAdd(orow + 8 * MUL + u * 3 + 0, w4s * cx);
    atomicAdd(orow + 8 * MUL + u * 3 + 1, w4s * cy);
    atomicAdd(orow + 8 * MUL + u * 3 + 2, w4s * cz);
}

extern "C" void kernel_launch(void* const* d_in, const int* in_sizes, int n_in,
                              void* d_out, int out_size, void* d_ws, size_t ws_size,
                              hipStream_t stream) {
    const float* x           = (const float*)d_in[0];
    const float* edge_attr   = (const float*)d_in[1];
    const float* edge_weight = (const float*)d_in[2];
    const int*   edge_dst    = (const int*)d_in[3];
    const int*   edge_src    = (const int*)d_in[4];
    float* out = (float*)d_out;

    // d_out is re-poisoned to 0xAA before every timed launch: zero it here.
    hipMemsetAsync(out, 0, (size_t)out_size * sizeof(float), stream);

    const int threads = 256;
    const long long total = (long long)N_EDGES * 32;
    const int blocks = (int)((total + threads - 1) / threads);
    tp_scatter_kernel<<<blocks, threads, 0, stream>>>(
        x, edge_attr, edge_weight, edge_dst, edge_src, out);
}

// Round 2
// 905.728 us; speedup vs baseline: 3.2042x; 3.2042x over previous
//
#include <hip/hip_runtime.h>

#define MUL 32
#define N_NODES 50000
#define N_EDGES 800000
#define ROW_OUT 352   // 11*MUL
#define ROW_X 128     // 4*MUL
#define ROW_W 160     // 5*MUL

#define INV_SQRT3 0.57735026918962576f
#define INV_SQRT2 0.70710678118654752f

#define SCAN_THREADS 1024

// ---------------- Phase 1: histogram of edge_dst ----------------
__global__ __launch_bounds__(256) void hist_kernel(
    const int* __restrict__ edge_dst, int* __restrict__ counts)
{
    int e = blockIdx.x * blockDim.x + threadIdx.x;
    if (e < N_EDGES) atomicAdd(&counts[edge_dst[e]], 1);
}

// ---------------- Phase 2: exclusive scan (single block) ----------------
__global__ __launch_bounds__(SCAN_THREADS) void scan_kernel(
    const int* __restrict__ counts, int* __restrict__ offsets,
    int* __restrict__ cursor)
{
    __shared__ int lds[SCAN_THREADS];
    const int t = threadIdx.x;
    int carry = 0;
    for (int base = 0; base < N_NODES; base += SCAN_THREADS) {
        int i = base + t;
        int v = (i < N_NODES) ? counts[i] : 0;
        lds[t] = v;
        __syncthreads();
        for (int off = 1; off < SCAN_THREADS; off <<= 1) {
            int add = (t >= off) ? lds[t - off] : 0;
            __syncthreads();
            lds[t] += add;
            __syncthreads();
        }
        int incl = lds[t];
        int excl = incl - v + carry;
        if (i < N_NODES) { offsets[i] = excl; cursor[i] = excl; }
        carry += lds[SCAN_THREADS - 1];
        __syncthreads();
    }
}

// ---------------- Phase 3: fill CSR edge list ----------------
__global__ __launch_bounds__(256) void fill_kernel(
    const int* __restrict__ edge_dst, int* __restrict__ cursor,
    int* __restrict__ edge_ids)
{
    int e = blockIdx.x * blockDim.x + threadIdx.x;
    if (e < N_EDGES) {
        int p = atomicAdd(&cursor[edge_dst[e]], 1);
        edge_ids[p] = e;
    }
}

// ---------------- Phase 4: gather-accumulate, one wave per node ----------------
// Wave of 64 = two half-waves; half h processes edges j = h, h+2, h+4, ...
// Lane u (0..31) owns mul-channel u. 11 register accumulators per lane.
// Halves combined via shfl, then lanes 0..31 store the 352-float row once.
__global__ __launch_bounds__(256) void gather_kernel(
    const float* __restrict__ x,
    const float* __restrict__ edge_attr,
    const float* __restrict__ edge_weight,
    const int*   __restrict__ edge_src,
    const int*   __restrict__ offsets,
    const int*   __restrict__ counts,
    const int*   __restrict__ edge_ids,
    float*       __restrict__ out)
{
    const int wave_in_block = threadIdx.x >> 6;
    const int n = blockIdx.x * (blockDim.x >> 6) + wave_in_block;
    if (n >= N_NODES) return;

    const int lane = threadIdx.x & 63;
    const int half = lane >> 5;
    const int u = lane & 31;

    const int start = offsets[n];
    const int deg = counts[n];

    float acc0 = 0.f;
    float acc1x = 0.f, acc1y = 0.f, acc1z = 0.f;
    float acc2x = 0.f, acc2y = 0.f, acc2z = 0.f;
    float acc3 = 0.f;
    float acc4x = 0.f, acc4y = 0.f, acc4z = 0.f;

    for (int j = half; j < deg; j += 2) {
        const int e = edge_ids[start + j];
        const int src = edge_src[e];

        const float4 a = *reinterpret_cast<const float4*>(edge_attr + (size_t)e * 4);
        const float a0  = a.x;
        const float a1x = a.y, a1y = a.z, a1z = a.w;

        const float* wrow = edge_weight + (size_t)e * ROW_W;
        const float w0 = wrow[0 * MUL + u];
        const float w1 = wrow[1 * MUL + u];
        const float w2 = wrow[2 * MUL + u];
        const float w3 = wrow[3 * MUL + u];
        const float w4 = wrow[4 * MUL + u];

        const float* xrow = x + (size_t)src * ROW_X;
        const float xs0 = xrow[u];
        const float x1x = xrow[MUL + u * 3 + 0];
        const float x1y = xrow[MUL + u * 3 + 1];
        const float x1z = xrow[MUL + u * 3 + 2];

        acc0 += w0 * xs0 * a0;

        const float w1xs0 = w1 * xs0;
        acc1x += w1xs0 * a1x;
        acc1y += w1xs0 * a1y;
        acc1z += w1xs0 * a1z;

        const float w2a0 = w2 * a0;
        acc2x += w2a0 * x1x;
        acc2y += w2a0 * x1y;
        acc2z += w2a0 * x1z;

        const float dot = x1x * a1x + x1y * a1y + x1z * a1z;
        acc3 += w3 * dot * INV_SQRT3;

        const float cx = x1y * a1z - x1z * a1y;
        const float cy = x1z * a1x - x1x * a1z;
        const float cz = x1x * a1y - x1y * a1x;
        const float w4s = w4 * INV_SQRT2;
        acc4x += w4s * cx;
        acc4y += w4s * cy;
        acc4z += w4s * cz;
    }

    // combine the two half-waves (lanes 0..31 += lanes 32..63)
    acc0  += __shfl_down(acc0, 32);
    acc1x += __shfl_down(acc1x, 32);
    acc1y += __shfl_down(acc1y, 32);
    acc1z += __shfl_down(acc1z, 32);
    acc2x += __shfl_down(acc2x, 32);
    acc2y += __shfl_down(acc2y, 32);
    acc2z += __shfl_down(acc2z, 32);
    acc3  += __shfl_down(acc3, 32);
    acc4x += __shfl_down(acc4x, 32);
    acc4y += __shfl_down(acc4y, 32);
    acc4z += __shfl_down(acc4z, 32);

    if (half == 0) {
        float* orow = out + (size_t)n * ROW_OUT;
        orow[u] = acc0;
        orow[1 * MUL + u * 3 + 0] = acc1x;
        orow[1 * MUL + u * 3 + 1] = acc1y;
        orow[1 * MUL + u * 3 + 2] = acc1z;
        orow[4 * MUL + u * 3 + 0] = acc2x;
        orow[4 * MUL + u * 3 + 1] = acc2y;
        orow[4 * MUL + u * 3 + 2] = acc2z;
        orow[7 * MUL + u] = acc3;
        orow[8 * MUL + u * 3 + 0] = acc4x;
        orow[8 * MUL + u * 3 + 1] = acc4y;
        orow[8 * MUL + u * 3 + 2] = acc4z;
    }
}

extern "C" void kernel_launch(void* const* d_in, const int* in_sizes, int n_in,
                              void* d_out, int out_size, void* d_ws, size_t ws_size,
                              hipStream_t stream) {
    const float* x           = (const float*)d_in[0];
    const float* edge_attr   = (const float*)d_in[1];
    const float* edge_weight = (const float*)d_in[2];
    const int*   edge_dst    = (const int*)d_in[3];
    const int*   edge_src    = (const int*)d_in[4];
    float* out = (float*)d_out;

    // workspace layout (ints): counts[50000] | offsets[50000] | cursor[50000] | edge_ids[800000]
    int* counts   = (int*)d_ws;
    int* offsets  = counts + N_NODES;
    int* cursor   = offsets + N_NODES;
    int* edge_ids = cursor + N_NODES;

    hipMemsetAsync(counts, 0, (size_t)N_NODES * sizeof(int), stream);

    const int eb = (N_EDGES + 255) / 256;
    hist_kernel<<<eb, 256, 0, stream>>>(edge_dst, counts);
    scan_kernel<<<1, SCAN_THREADS, 0, stream>>>(counts, offsets, cursor);
    fill_kernel<<<eb, 256, 0, stream>>>(edge_dst, cursor, edge_ids);

    // one 64-lane wave per node, 4 waves per block
    const int waves_per_block = 4;
    const int nb = (N_NODES + waves_per_block - 1) / waves_per_block;
    gather_kernel<<<nb, waves_per_block * 64, 0, stream>>>(
        x, edge_attr, edge_weight, edge_src, offsets, counts, edge_ids, out);
}